// Round 3
// baseline (3614.701 us; speedup 1.0000x reference)
//
#include <hip/hip_runtime.h>

// ---------------------------------------------------------------------------
// Bidirectional LSTM, B=32, T=512, I=768, H=512. Output = relu([h_f(T-1), h_b_first]) [32,1024] fp32.
// Plan:
//   K0 cvt_w:    w_ih_f fp32 -> bf16 (ws)
//   K1 gx:       gx[t][wg][gate][b][j] = x[b,t,:]@w_ih_f^T + b_ih_f + b_hh_f   (bf16, 64 MB ws)
//   K2 bwd:      single LSTM cell on x[:,T-1,:] with (h0[1],c0[1]) -> out[:,512:1024]
//   K3 fwd:      persistent 32-WG kernel, 512 steps.
//
// Round-3 change: the per-step grid sync no longer uses a contended fetch_add
// (32 same-address RMWs serialized ~100-150ns each = the 6 us/step). Instead:
// 32 per-producer flags in ONE 128-B cacheline, written with plain relaxed
// device-scope stores (no contention), polled by wave 0 with a single
// coalesced 32-lane load per iteration. gx prefetch is issued before the wait
// so the publish-side vmcnt(0) drain never waits on HBM.
// ---------------------------------------------------------------------------

typedef __attribute__((ext_vector_type(4))) float         floatx4;
typedef __attribute__((ext_vector_type(4))) unsigned int  uintx4;
typedef __attribute__((ext_vector_type(8))) unsigned short ushortx8;
typedef __attribute__((ext_vector_type(4))) unsigned short ushortx4;
typedef __attribute__((ext_vector_type(8))) __bf16        bf16x8;

#define NBLK 32  // persistent workgroups in fwd kernel

__device__ __forceinline__ unsigned short f2bf(float f) {
  unsigned u = __builtin_bit_cast(unsigned, f);
  return (unsigned short)((u + 0x7fffu + ((u >> 16) & 1u)) >> 16);  // RNE
}
__device__ __forceinline__ float bf2f(unsigned short h) {
  unsigned u = ((unsigned)h) << 16;
  return __builtin_bit_cast(float, u);
}
__device__ __forceinline__ floatx4 mfma_bf16(ushortx8 a, ushortx8 b, floatx4 c) {
  return __builtin_amdgcn_mfma_f32_16x16x32_bf16(
      __builtin_bit_cast(bf16x8, a), __builtin_bit_cast(bf16x8, b), c, 0, 0, 0);
}
__device__ __forceinline__ float sigmoidf_(float x) { return 1.f / (1.f + __expf(-x)); }
__device__ __forceinline__ float tanhf_(float x) {
  float ax = fabsf(x);
  float e = __expf(-2.f * ax);
  float r = (1.f - e) / (1.f + e);
  return x < 0.f ? -r : r;
}

// --------------------------- K0: weight convert ----------------------------
__global__ void cvt_w_kernel(const float* __restrict__ src, unsigned short* __restrict__ dst, int n) {
  int i = (blockIdx.x * 256 + threadIdx.x) * 4;
  if (i < n) {
    floatx4 v = *reinterpret_cast<const floatx4*>(src + i);
    ushortx4 o;
    o[0] = f2bf(v[0]); o[1] = f2bf(v[1]); o[2] = f2bf(v[2]); o[3] = f2bf(v[3]);
    *reinterpret_cast<ushortx4*>(dst + i) = o;
  }
}

// --------------------------- K1: gx precompute -----------------------------
// grid (8, 512): blockIdx.y = t, blockIdx.x = nb (4 wg-slices each).
// gxbuf layout: [t][wg][gate][b][j] bf16, block (t,wg) = 2048 elements (4 KB).
__global__ __launch_bounds__(256) void gx_kernel(
    const float* __restrict__ x, const unsigned short* __restrict__ w_bf,
    const float* __restrict__ b_ih, const float* __restrict__ b_hh,
    unsigned short* __restrict__ gxbuf) {
  const int t = blockIdx.y;
  const int nb = blockIdx.x;
  const int tid = threadIdx.x;
  const int wave = tid >> 6;       // gate 0..3
  const int lane = tid & 63;
  const int l15 = lane & 15;
  const int lq = lane >> 4;

  __shared__ __align__(16) unsigned short x_lds[32][776];  // 768 + pad 8

  // Stage x[b][t][:] fp32 -> bf16 LDS. 8 threads per row, 24 float4 each.
  {
    const int row = tid >> 3, c8 = tid & 7;
    const floatx4* src = reinterpret_cast<const floatx4*>(x + ((size_t)row * 512 + t) * 768);
#pragma unroll
    for (int m = 0; m < 24; ++m) {
      int col4 = c8 + m * 8;
      floatx4 v = src[col4];
      ushortx4 o;
      o[0] = f2bf(v[0]); o[1] = f2bf(v[1]); o[2] = f2bf(v[2]); o[3] = f2bf(v[3]);
      *reinterpret_cast<ushortx4*>(&x_lds[row][col4 * 4]) = o;
    }
  }
  __syncthreads();

  const int wgs = nb * 4;
  const ushortx8* brow[4];
#pragma unroll
  for (int nt = 0; nt < 4; ++nt) {
    int n = wave * 512 + (wgs + nt) * 16 + l15;
    brow[nt] = reinterpret_cast<const ushortx8*>(w_bf + (size_t)n * 768);
  }

  floatx4 acc[4][2];
#pragma unroll
  for (int nt = 0; nt < 4; ++nt) { acc[nt][0] = (floatx4)0.f; acc[nt][1] = (floatx4)0.f; }

  for (int q = 0; q < 24; ++q) {
    ushortx8 a0 = *reinterpret_cast<const ushortx8*>(&x_lds[l15][q * 32 + lq * 8]);
    ushortx8 a1 = *reinterpret_cast<const ushortx8*>(&x_lds[16 + l15][q * 32 + lq * 8]);
#pragma unroll
    for (int nt = 0; nt < 4; ++nt) {
      ushortx8 bf = brow[nt][q * 4 + lq];
      acc[nt][0] = mfma_bf16(a0, bf, acc[nt][0]);
      acc[nt][1] = mfma_bf16(a1, bf, acc[nt][1]);
    }
  }

  // Epilogue: add bias, write bf16 in [gate][b][j] order per (t,wg) block.
#pragma unroll
  for (int nt = 0; nt < 4; ++nt) {
    int wg = wgs + nt;
    int N = wave * 512 + wg * 16 + l15;
    float bias = b_ih[N] + b_hh[N];
    unsigned short* dst = gxbuf + ((size_t)(t * 32 + wg)) * 2048 + wave * 512 + l15;
#pragma unroll
    for (int m = 0; m < 2; ++m)
#pragma unroll
      for (int r = 0; r < 4; ++r) {
        int b = m * 16 + lq * 4 + r;
        dst[b * 16] = f2bf(acc[nt][m][r] + bias);
      }
  }
}

// --------------------------- K2: backward single step ----------------------
// hs_b[0] = one LSTM cell on x[:,511,:] from (h0[1], c0[1]). grid = 32 WGs.
__global__ __launch_bounds__(256) void bwd_kernel(
    const float* __restrict__ x, const float* __restrict__ h0, const float* __restrict__ c0,
    const float* __restrict__ w_ih_b, const float* __restrict__ w_hh_b,
    const float* __restrict__ b_ih_b, const float* __restrict__ b_hh_b,
    float* __restrict__ out) {
  const int wg = blockIdx.x;
  const int tid = threadIdx.x;
  const int wave = tid >> 6;
  const int lane = tid & 63;
  const int l15 = lane & 15;
  const int lq = lane >> 4;

  __shared__ __align__(16) unsigned short cat_lds[32][1288];  // [b][x(768) | h0(512)] + pad 8
  __shared__ __align__(16) float gate_lds[4][32][16];

  {
    const int row = tid >> 3, o8 = tid & 7;
    const floatx4* xs = reinterpret_cast<const floatx4*>(x + ((size_t)row * 512 + 511) * 768);
#pragma unroll
    for (int m = 0; m < 24; ++m) {
      int col4 = o8 + m * 8;
      floatx4 v = xs[col4];
      ushortx4 o;
      o[0] = f2bf(v[0]); o[1] = f2bf(v[1]); o[2] = f2bf(v[2]); o[3] = f2bf(v[3]);
      *reinterpret_cast<ushortx4*>(&cat_lds[row][col4 * 4]) = o;
    }
    const floatx4* hs = reinterpret_cast<const floatx4*>(h0 + (size_t)(32 + row) * 512);
#pragma unroll
    for (int m = 0; m < 16; ++m) {
      int col4 = o8 + m * 8;
      floatx4 v = hs[col4];
      ushortx4 o;
      o[0] = f2bf(v[0]); o[1] = f2bf(v[1]); o[2] = f2bf(v[2]); o[3] = f2bf(v[3]);
      *reinterpret_cast<ushortx4*>(&cat_lds[row][768 + col4 * 4]) = o;
    }
  }
  __syncthreads();

  const int n = wave * 512 + wg * 16 + l15;  // gate-column row of concat weight
  floatx4 acc0 = (floatx4)0.f, acc1 = (floatx4)0.f;
  for (int q = 0; q < 40; ++q) {
    int k0 = q * 32;
    const float* wsrc = (k0 < 768) ? (w_ih_b + (size_t)n * 768 + k0 + lq * 8)
                                   : (w_hh_b + (size_t)n * 512 + (k0 - 768) + lq * 8);
    ushortx8 bf;
#pragma unroll
    for (int j = 0; j < 8; ++j) bf[j] = f2bf(wsrc[j]);
    ushortx8 a0 = *reinterpret_cast<const ushortx8*>(&cat_lds[l15][k0 + lq * 8]);
    ushortx8 a1 = *reinterpret_cast<const ushortx8*>(&cat_lds[16 + l15][k0 + lq * 8]);
    acc0 = mfma_bf16(a0, bf, acc0);
    acc1 = mfma_bf16(a1, bf, acc1);
  }
#pragma unroll
  for (int r = 0; r < 4; ++r) {
    gate_lds[wave][lq * 4 + r][l15] = acc0[r];
    gate_lds[wave][16 + lq * 4 + r][l15] = acc1[r];
  }
  __syncthreads();

  {
    const int jj = tid & 15;
    const int b0 = tid >> 4;
    const int col = wg * 16 + jj;
    float bi[4];
#pragma unroll
    for (int g = 0; g < 4; ++g) bi[g] = b_ih_b[g * 512 + col] + b_hh_b[g * 512 + col];
#pragma unroll
    for (int half = 0; half < 2; ++half) {
      int b = b0 + half * 16;
      float gi = sigmoidf_(gate_lds[0][b][jj] + bi[0]);
      float gf = sigmoidf_(gate_lds[1][b][jj] + bi[1]);
      float gg = tanhf_(gate_lds[2][b][jj] + bi[2]);
      float go = sigmoidf_(gate_lds[3][b][jj] + bi[3]);
      float c = gf * c0[(size_t)(32 + b) * 512 + col] + gi * gg;
      float h = go * tanhf_(c);
      out[(size_t)b * 1024 + 512 + col] = fmaxf(h, 0.f);
    }
  }
}

// --------------------------- K3: persistent forward ------------------------
// 32 WGs, WG wg owns hidden cols [wg*16, wg*16+16). 512 steps.
// Sync: 32 per-producer monotonic flags in one 128-B line. flags[wg] = s means
// "h_{s-1} (slot (s-1)&1) is visible at the coherence point". No RMWs anywhere.
__global__ __launch_bounds__(256, 1) void lstm_fwd_kernel(
    const float* __restrict__ w_hh, const unsigned short* __restrict__ gxbuf,
    const float* __restrict__ h0, const float* __restrict__ c0,
    unsigned* __restrict__ gbuf32, unsigned* __restrict__ flags,
    float* __restrict__ out) {
  const int wg = blockIdx.x;
  const int tid = threadIdx.x;
  const int wave = tid >> 6;  // gate 0..3
  const int lane = tid & 63;
  const int l15 = lane & 15;
  const int lq = lane >> 4;

  __shared__ __align__(16) unsigned short h_lds[32][520];    // [b][k], pad 8 -> 2-way banks (free)
  __shared__ __align__(16) float gate_lds[4][32][16];
  __shared__ __align__(16) unsigned short gx_lds[2][2048];   // double-buffered [gate][b][j]

  // One-time: w_hh B-fragments resident in VGPRs (16 k-steps x 8 bf16).
  ushortx8 wfrag[16];
  {
    const int n = wave * 512 + wg * 16 + l15;
    const float* wrow = w_hh + (size_t)n * 512 + lq * 8;
#pragma unroll
    for (int q = 0; q < 16; ++q) {
      ushortx8 f;
#pragma unroll
      for (int j = 0; j < 8; ++j) f[j] = f2bf(wrow[q * 32 + j]);
      wfrag[q] = f;
    }
  }

  // Per-thread cell state: 1 batch row, 2 adjacent cols (packs to one uint32 store).
  const int b_ = tid >> 3;           // 0..31
  const int j0 = (tid & 7) * 2;      // 0,2,..,14
  const int col0 = wg * 16 + j0;
  float c_0 = c0[(size_t)b_ * 512 + col0];
  float c_1 = c0[(size_t)b_ * 512 + col0 + 1];

  // Publish h0 into slot 0 (packed bf16x2, device-scope relaxed), then flag=1.
  {
    unsigned v = (unsigned)f2bf(h0[(size_t)b_ * 512 + col0]) |
                 ((unsigned)f2bf(h0[(size_t)b_ * 512 + col0 + 1]) << 16);
    __hip_atomic_store(&gbuf32[b_ * 256 + (col0 >> 1)], v, __ATOMIC_RELAXED, __HIP_MEMORY_SCOPE_AGENT);
  }
  asm volatile("s_waitcnt vmcnt(0)" ::: "memory");
  __syncthreads();
  if (tid == 0)
    __hip_atomic_store(&flags[wg], 1u, __ATOMIC_RELAXED, __HIP_MEMORY_SCOPE_AGENT);

  const uintx4* gxp = reinterpret_cast<const uintx4*>(gxbuf);
  uintx4 gxreg = gxp[(size_t)(0 * 32 + wg) * 256 + tid];  // prefetch t=0

#pragma unroll 1
  for (int t = 0; t < 512; ++t) {
    // gx[t] regs -> LDS (buffer t&1, read two syncs later); prefetch gx[t+1].
    *reinterpret_cast<uintx4*>(&gx_lds[t & 1][tid * 8]) = gxreg;
    if (t + 1 < 512) gxreg = gxp[(size_t)((t + 1) * 32 + wg) * 256 + tid];

    // Wait: all 32 producer flags >= t+1. One coalesced 128-B load per poll.
    if (wave == 0) {
      const unsigned target = (unsigned)(t + 1);
      bool done;
      do {
        unsigned v = target;
        if (lane < 32)
          v = __hip_atomic_load(&flags[lane], __ATOMIC_RELAXED, __HIP_MEMORY_SCOPE_AGENT);
        done = (v >= target);
      } while (!__all(done));
    }
    __syncthreads();

    // Broadcast h_t: coherence point -> LDS (128 B per thread).
    const unsigned long long* hsrc =
        reinterpret_cast<const unsigned long long*>(gbuf32 + (size_t)(t & 1) * 8192);
#pragma unroll
    for (int k = 0; k < 16; ++k) {
      int f = tid + k * 256;  // 0..4095 uint64s; 128 per batch row
      unsigned long long v = __hip_atomic_load(&hsrc[f], __ATOMIC_RELAXED, __HIP_MEMORY_SCOPE_AGENT);
      *reinterpret_cast<unsigned long long*>(&h_lds[f >> 7][(f & 127) * 4]) = v;
    }
    __syncthreads();

    // gates(preact) = h @ w_hh^T for this wave's 16 gate-cols.
    floatx4 acc0 = (floatx4)0.f, acc1 = (floatx4)0.f;
#pragma unroll
    for (int q = 0; q < 16; ++q) {
      ushortx8 a0 = *reinterpret_cast<const ushortx8*>(&h_lds[l15][q * 32 + lq * 8]);
      ushortx8 a1 = *reinterpret_cast<const ushortx8*>(&h_lds[16 + l15][q * 32 + lq * 8]);
      acc0 = mfma_bf16(a0, wfrag[q], acc0);
      acc1 = mfma_bf16(a1, wfrag[q], acc1);
    }
#pragma unroll
    for (int r = 0; r < 4; ++r) {
      gate_lds[wave][lq * 4 + r][l15] = acc0[r];
      gate_lds[wave][16 + lq * 4 + r][l15] = acc1[r];
    }
    __syncthreads();

    // Combine: i,f,g,o -> c,h for (b_, col0) and (b_, col0+1).
    {
      const unsigned short* gx = gx_lds[t & 1];
      float i0 = sigmoidf_(gate_lds[0][b_][j0] + bf2f(gx[(0 * 32 + b_) * 16 + j0]));
      float f0 = sigmoidf_(gate_lds[1][b_][j0] + bf2f(gx[(1 * 32 + b_) * 16 + j0]));
      float g0 = tanhf_(gate_lds[2][b_][j0] + bf2f(gx[(2 * 32 + b_) * 16 + j0]));
      float o0 = sigmoidf_(gate_lds[3][b_][j0] + bf2f(gx[(3 * 32 + b_) * 16 + j0]));
      c_0 = f0 * c_0 + i0 * g0;
      float ha = o0 * tanhf_(c_0);

      float i1 = sigmoidf_(gate_lds[0][b_][j0 + 1] + bf2f(gx[(0 * 32 + b_) * 16 + j0 + 1]));
      float f1 = sigmoidf_(gate_lds[1][b_][j0 + 1] + bf2f(gx[(1 * 32 + b_) * 16 + j0 + 1]));
      float g1 = tanhf_(gate_lds[2][b_][j0 + 1] + bf2f(gx[(2 * 32 + b_) * 16 + j0 + 1]));
      float o1 = sigmoidf_(gate_lds[3][b_][j0 + 1] + bf2f(gx[(3 * 32 + b_) * 16 + j0 + 1]));
      c_1 = f1 * c_1 + i1 * g1;
      float hb = o1 * tanhf_(c_1);

      // Publish h_{t+1} (slot (t+1)&1) as one packed device-scope store.
      unsigned v = (unsigned)f2bf(ha) | ((unsigned)f2bf(hb) << 16);
      unsigned* hdst = gbuf32 + (size_t)((t + 1) & 1) * 8192;
      __hip_atomic_store(&hdst[b_ * 256 + (col0 >> 1)], v, __ATOMIC_RELAXED, __HIP_MEMORY_SCOPE_AGENT);
      if (t == 511) {
        out[(size_t)b_ * 1024 + col0] = fmaxf(ha, 0.f);
        out[(size_t)b_ * 1024 + col0 + 1] = fmaxf(hb, 0.f);
      }
    }

    // Arrive: per-wave drain of the publish stores, then a plain flag store.
    asm volatile("s_waitcnt vmcnt(0)" ::: "memory");
    __syncthreads();
    if (tid == 0)
      __hip_atomic_store(&flags[wg], (unsigned)(t + 2), __ATOMIC_RELAXED, __HIP_MEMORY_SCOPE_AGENT);
  }
}

// ---------------------------------------------------------------------------
extern "C" void kernel_launch(void* const* d_in, const int* in_sizes, int n_in,
                              void* d_out, int out_size, void* d_ws, size_t ws_size,
                              hipStream_t stream) {
  const float* x      = (const float*)d_in[0];
  const float* h0     = (const float*)d_in[1];
  const float* c0     = (const float*)d_in[2];
  const float* w_ih_f = (const float*)d_in[3];
  const float* w_hh_f = (const float*)d_in[4];
  const float* b_ih_f = (const float*)d_in[5];
  const float* b_hh_f = (const float*)d_in[6];
  const float* w_ih_b = (const float*)d_in[7];
  const float* w_hh_b = (const float*)d_in[8];
  const float* b_ih_b = (const float*)d_in[9];
  const float* b_hh_b = (const float*)d_in[10];
  float* out = (float*)d_out;

  char* ws = (char*)d_ws;
  unsigned short* gxbuf = (unsigned short*)(ws);                                  // 64 MB
  unsigned short* wihbf = (unsigned short*)(ws + (size_t)67108864);               // 3 MB
  unsigned* gbuf32      = (unsigned*)(ws + (size_t)67108864 + 3145728);           // 64 KB (h double buffer)
  unsigned* flags       = (unsigned*)(ws + (size_t)67108864 + 3145728 + 65536);   // 32 flags, one line

  hipMemsetAsync(flags, 0, 256, stream);
  hipLaunchKernelGGL(cvt_w_kernel, dim3(1536), dim3(256), 0, stream, w_ih_f, wihbf, 1572864);
  hipLaunchKernelGGL(gx_kernel, dim3(8, 512), dim3(256), 0, stream, x, wihbf, b_ih_f, b_hh_f, gxbuf);
  hipLaunchKernelGGL(bwd_kernel, dim3(32), dim3(256), 0, stream, x, h0, c0,
                     w_ih_b, w_hh_b, b_ih_b, b_hh_b, out);
  hipLaunchKernelGGL(lstm_fwd_kernel, dim3(NBLK), dim3(256), 0, stream,
                     w_hh_f, gxbuf, h0, c0, gbuf32, flags, out);
}

// Round 4
// 1970.163 us; speedup vs baseline: 1.8347x; 1.8347x over previous
//
#include <hip/hip_runtime.h>

// ---------------------------------------------------------------------------
// Bidirectional LSTM, B=32, T=512, I=768, H=512. Output = relu([h_f(T-1), h_b_first]) [32,1024] fp32.
//   K0 cvt_w:    w_ih_f fp32 -> bf16 (ws)
//   K1 gx:       gx[t][wg][gate][b][j] = x[b,t,:]@w_ih_f^T + b_ih_f + b_hh_f   (bf16, 64 MB ws)
//   K2 bwd:      single LSTM cell on x[:,T-1,:] with (h0[1],c0[1]) -> out[:,512:1024]
//   K3 fwd:      persistent 32 worker WGs + 224 burner WGs, 512 steps.
//
// Round-4 changes:
//  (1) Tagged-mailbox h exchange: every h element pair is ONE atomic u64
//      {data:hi32 | tag:lo32}. Producers fire-and-forget; consumers poll-read
//      the data words until tag==t+1. Discovery+read merge into ~1 round trip;
//      no vmcnt drain, no flags, no release/acquire anywhere on the hot path.
//      Two slots (t&1) + the WG-internal barrier between h-read and publish
//      make overwrite races impossible.
//  (2) Burner blocks (blockIdx>=32) run a dependent-FMA spin until workers
//      finish, to keep engine clocks boosted (tests the DVFS theory).
// ---------------------------------------------------------------------------

typedef __attribute__((ext_vector_type(4))) float         floatx4;
typedef __attribute__((ext_vector_type(4))) unsigned int  uintx4;
typedef __attribute__((ext_vector_type(8))) unsigned short ushortx8;
typedef __attribute__((ext_vector_type(4))) unsigned short ushortx4;
typedef __attribute__((ext_vector_type(8))) __bf16        bf16x8;

#define NBLK 32        // worker workgroups
#define GRID_TOTAL 256 // workers + burners
#define DONE_MAGIC 0xDEADBEEFu

__device__ __forceinline__ unsigned short f2bf(float f) {
  unsigned u = __builtin_bit_cast(unsigned, f);
  return (unsigned short)((u + 0x7fffu + ((u >> 16) & 1u)) >> 16);  // RNE
}
__device__ __forceinline__ float bf2f(unsigned short h) {
  unsigned u = ((unsigned)h) << 16;
  return __builtin_bit_cast(float, u);
}
__device__ __forceinline__ floatx4 mfma_bf16(ushortx8 a, ushortx8 b, floatx4 c) {
  return __builtin_amdgcn_mfma_f32_16x16x32_bf16(
      __builtin_bit_cast(bf16x8, a), __builtin_bit_cast(bf16x8, b), c, 0, 0, 0);
}
__device__ __forceinline__ float sigmoidf_(float x) { return 1.f / (1.f + __expf(-x)); }
__device__ __forceinline__ float tanhf_(float x) {
  float ax = fabsf(x);
  float e = __expf(-2.f * ax);
  float r = (1.f - e) / (1.f + e);
  return x < 0.f ? -r : r;
}

// --------------------------- K0: weight convert ----------------------------
__global__ void cvt_w_kernel(const float* __restrict__ src, unsigned short* __restrict__ dst, int n) {
  int i = (blockIdx.x * 256 + threadIdx.x) * 4;
  if (i < n) {
    floatx4 v = *reinterpret_cast<const floatx4*>(src + i);
    ushortx4 o;
    o[0] = f2bf(v[0]); o[1] = f2bf(v[1]); o[2] = f2bf(v[2]); o[3] = f2bf(v[3]);
    *reinterpret_cast<ushortx4*>(dst + i) = o;
  }
}

// --------------------------- K1: gx precompute -----------------------------
// grid (8, 512): blockIdx.y = t, blockIdx.x = nb (4 wg-slices each).
// gxbuf layout: [t][wg][gate][b][j] bf16, block (t,wg) = 2048 elements (4 KB).
__global__ __launch_bounds__(256) void gx_kernel(
    const float* __restrict__ x, const unsigned short* __restrict__ w_bf,
    const float* __restrict__ b_ih, const float* __restrict__ b_hh,
    unsigned short* __restrict__ gxbuf) {
  const int t = blockIdx.y;
  const int nb = blockIdx.x;
  const int tid = threadIdx.x;
  const int wave = tid >> 6;       // gate 0..3
  const int lane = tid & 63;
  const int l15 = lane & 15;
  const int lq = lane >> 4;

  __shared__ __align__(16) unsigned short x_lds[32][776];  // 768 + pad 8

  {
    const int row = tid >> 3, c8 = tid & 7;
    const floatx4* src = reinterpret_cast<const floatx4*>(x + ((size_t)row * 512 + t) * 768);
#pragma unroll
    for (int m = 0; m < 24; ++m) {
      int col4 = c8 + m * 8;
      floatx4 v = src[col4];
      ushortx4 o;
      o[0] = f2bf(v[0]); o[1] = f2bf(v[1]); o[2] = f2bf(v[2]); o[3] = f2bf(v[3]);
      *reinterpret_cast<ushortx4*>(&x_lds[row][col4 * 4]) = o;
    }
  }
  __syncthreads();

  const int wgs = nb * 4;
  const ushortx8* brow[4];
#pragma unroll
  for (int nt = 0; nt < 4; ++nt) {
    int n = wave * 512 + (wgs + nt) * 16 + l15;
    brow[nt] = reinterpret_cast<const ushortx8*>(w_bf + (size_t)n * 768);
  }

  floatx4 acc[4][2];
#pragma unroll
  for (int nt = 0; nt < 4; ++nt) { acc[nt][0] = (floatx4)0.f; acc[nt][1] = (floatx4)0.f; }

  for (int q = 0; q < 24; ++q) {
    ushortx8 a0 = *reinterpret_cast<const ushortx8*>(&x_lds[l15][q * 32 + lq * 8]);
    ushortx8 a1 = *reinterpret_cast<const ushortx8*>(&x_lds[16 + l15][q * 32 + lq * 8]);
#pragma unroll
    for (int nt = 0; nt < 4; ++nt) {
      ushortx8 bf = brow[nt][q * 4 + lq];
      acc[nt][0] = mfma_bf16(a0, bf, acc[nt][0]);
      acc[nt][1] = mfma_bf16(a1, bf, acc[nt][1]);
    }
  }

#pragma unroll
  for (int nt = 0; nt < 4; ++nt) {
    int wg = wgs + nt;
    int N = wave * 512 + wg * 16 + l15;
    float bias = b_ih[N] + b_hh[N];
    unsigned short* dst = gxbuf + ((size_t)(t * 32 + wg)) * 2048 + wave * 512 + l15;
#pragma unroll
    for (int m = 0; m < 2; ++m)
#pragma unroll
      for (int r = 0; r < 4; ++r) {
        int b = m * 16 + lq * 4 + r;
        dst[b * 16] = f2bf(acc[nt][m][r] + bias);
      }
  }
}

// --------------------------- K2: backward single step ----------------------
__global__ __launch_bounds__(256) void bwd_kernel(
    const float* __restrict__ x, const float* __restrict__ h0, const float* __restrict__ c0,
    const float* __restrict__ w_ih_b, const float* __restrict__ w_hh_b,
    const float* __restrict__ b_ih_b, const float* __restrict__ b_hh_b,
    float* __restrict__ out) {
  const int wg = blockIdx.x;
  const int tid = threadIdx.x;
  const int wave = tid >> 6;
  const int lane = tid & 63;
  const int l15 = lane & 15;
  const int lq = lane >> 4;

  __shared__ __align__(16) unsigned short cat_lds[32][1288];  // [b][x(768) | h0(512)] + pad 8
  __shared__ __align__(16) float gate_lds[4][32][16];

  {
    const int row = tid >> 3, o8 = tid & 7;
    const floatx4* xs = reinterpret_cast<const floatx4*>(x + ((size_t)row * 512 + 511) * 768);
#pragma unroll
    for (int m = 0; m < 24; ++m) {
      int col4 = o8 + m * 8;
      floatx4 v = xs[col4];
      ushortx4 o;
      o[0] = f2bf(v[0]); o[1] = f2bf(v[1]); o[2] = f2bf(v[2]); o[3] = f2bf(v[3]);
      *reinterpret_cast<ushortx4*>(&cat_lds[row][col4 * 4]) = o;
    }
    const floatx4* hs = reinterpret_cast<const floatx4*>(h0 + (size_t)(32 + row) * 512);
#pragma unroll
    for (int m = 0; m < 16; ++m) {
      int col4 = o8 + m * 8;
      floatx4 v = hs[col4];
      ushortx4 o;
      o[0] = f2bf(v[0]); o[1] = f2bf(v[1]); o[2] = f2bf(v[2]); o[3] = f2bf(v[3]);
      *reinterpret_cast<ushortx4*>(&cat_lds[row][768 + col4 * 4]) = o;
    }
  }
  __syncthreads();

  const int n = wave * 512 + wg * 16 + l15;
  floatx4 acc0 = (floatx4)0.f, acc1 = (floatx4)0.f;
  for (int q = 0; q < 40; ++q) {
    int k0 = q * 32;
    const float* wsrc = (k0 < 768) ? (w_ih_b + (size_t)n * 768 + k0 + lq * 8)
                                   : (w_hh_b + (size_t)n * 512 + (k0 - 768) + lq * 8);
    ushortx8 bf;
#pragma unroll
    for (int j = 0; j < 8; ++j) bf[j] = f2bf(wsrc[j]);
    ushortx8 a0 = *reinterpret_cast<const ushortx8*>(&cat_lds[l15][k0 + lq * 8]);
    ushortx8 a1 = *reinterpret_cast<const ushortx8*>(&cat_lds[16 + l15][k0 + lq * 8]);
    acc0 = mfma_bf16(a0, bf, acc0);
    acc1 = mfma_bf16(a1, bf, acc1);
  }
#pragma unroll
  for (int r = 0; r < 4; ++r) {
    gate_lds[wave][lq * 4 + r][l15] = acc0[r];
    gate_lds[wave][16 + lq * 4 + r][l15] = acc1[r];
  }
  __syncthreads();

  {
    const int jj = tid & 15;
    const int b0 = tid >> 4;
    const int col = wg * 16 + jj;
    float bi[4];
#pragma unroll
    for (int g = 0; g < 4; ++g) bi[g] = b_ih_b[g * 512 + col] + b_hh_b[g * 512 + col];
#pragma unroll
    for (int half = 0; half < 2; ++half) {
      int b = b0 + half * 16;
      float gi = sigmoidf_(gate_lds[0][b][jj] + bi[0]);
      float gf = sigmoidf_(gate_lds[1][b][jj] + bi[1]);
      float gg = tanhf_(gate_lds[2][b][jj] + bi[2]);
      float go = sigmoidf_(gate_lds[3][b][jj] + bi[3]);
      float c = gf * c0[(size_t)(32 + b) * 512 + col] + gi * gg;
      float h = go * tanhf_(c);
      out[(size_t)b * 1024 + 512 + col] = fmaxf(h, 0.f);
    }
  }
}

// --------------------------- K3: persistent forward ------------------------
// Workers (blockIdx<32): WG wg owns hidden cols [wg*16, wg*16+16), 512 steps.
// h exchange: gbuf64[slot][b*256 + col/2] = {bf16x2 data (hi32) | tag (lo32)},
// tag = t+1 for h_t in slot t&1. Atomic u64 store/load, relaxed, agent scope.
// Burners (blockIdx>=32): dependent-FMA spin until flags[0]==DONE_MAGIC.
__global__ __launch_bounds__(256, 1) void lstm_fwd_kernel(
    const float* __restrict__ w_hh, const unsigned short* __restrict__ gxbuf,
    const float* __restrict__ h0, const float* __restrict__ c0,
    unsigned long long* gbuf64, unsigned* flags, float* sink,
    float* __restrict__ out) {
  const int tid = threadIdx.x;

  if (blockIdx.x >= NBLK) {
    // ---- burner: keep the engine clock boosted until the workers finish ----
    __shared__ unsigned sdone;
    float a0 = 1.0f + 1e-7f * (float)(tid + 1);
    float a1 = 1.0f - 1e-7f * (float)(tid + 2);
    float a2 = 1.0f + 2e-7f * (float)(tid + 3);
    float a3 = 1.0f - 2e-7f * (float)(tid + 4);
    const float m0 = 0.99999994f;
    unsigned d;
    do {
#pragma unroll 8
      for (int i = 0; i < 2048; ++i) {
        a0 = fmaf(a0, m0, 1e-7f);
        a1 = fmaf(a1, m0, -1e-7f);
        a2 = fmaf(a2, m0, 2e-7f);
        a3 = fmaf(a3, m0, -2e-7f);
      }
      if (tid == 0)
        sdone = __hip_atomic_load(&flags[0], __ATOMIC_RELAXED, __HIP_MEMORY_SCOPE_AGENT);
      __syncthreads();
      d = sdone;
      __syncthreads();
    } while (d != DONE_MAGIC);
    if (a0 + a1 + a2 + a3 == 3.14159f) sink[blockIdx.x] = a0;  // keep the math alive
    return;
  }

  // ------------------------------- worker -----------------------------------
  const int wg = blockIdx.x;
  const int wave = tid >> 6;  // gate 0..3
  const int lane = tid & 63;
  const int l15 = lane & 15;
  const int lq = lane >> 4;

  __shared__ __align__(16) unsigned short h_lds[32][520];    // [b][k], pad 8 -> 2-way banks (free)
  __shared__ __align__(16) float gate_lds[4][32][16];
  __shared__ __align__(16) unsigned short gx_lds[2][2048];   // double-buffered [gate][b][j]

  // One-time: w_hh B-fragments resident in VGPRs (16 k-steps x 8 bf16).
  ushortx8 wfrag[16];
  {
    const int n = wave * 512 + wg * 16 + l15;
    const float* wrow = w_hh + (size_t)n * 512 + lq * 8;
#pragma unroll
    for (int q = 0; q < 16; ++q) {
      ushortx8 f;
#pragma unroll
      for (int j = 0; j < 8; ++j) f[j] = f2bf(wrow[q * 32 + j]);
      wfrag[q] = f;
    }
  }

  // Per-thread cell state: 1 batch row, 2 adjacent cols (one tagged u64 publish).
  const int b_ = tid >> 3;           // 0..31
  const int j0 = (tid & 7) * 2;      // 0,2,..,14
  const int col0 = wg * 16 + j0;
  float c_0 = c0[(size_t)b_ * 512 + col0];
  float c_1 = c0[(size_t)b_ * 512 + col0 + 1];

  // Publish h0 into slot 0 with tag 1. Fire-and-forget.
  {
    unsigned data = (unsigned)f2bf(h0[(size_t)b_ * 512 + col0]) |
                    ((unsigned)f2bf(h0[(size_t)b_ * 512 + col0 + 1]) << 16);
    unsigned long long w = ((unsigned long long)data << 32) | 1ull;
    __hip_atomic_store(&gbuf64[b_ * 256 + (col0 >> 1)], w, __ATOMIC_RELAXED, __HIP_MEMORY_SCOPE_AGENT);
  }

  const uintx4* gxp = reinterpret_cast<const uintx4*>(gxbuf);
  uintx4 gxreg = gxp[(size_t)(0 * 32 + wg) * 256 + tid];  // prefetch t=0

#pragma unroll 1
  for (int t = 0; t < 512; ++t) {
    // gx[t] regs -> LDS (buffer t&1); prefetch gx[t+1].
    *reinterpret_cast<uintx4*>(&gx_lds[t & 1][tid * 8]) = gxreg;
    if (t + 1 < 512) gxreg = gxp[(size_t)((t + 1) * 32 + wg) * 256 + tid];

    // Poll-read h_t: 32 tagged u64 words per thread from slot t&1.
    {
      unsigned long long* src = gbuf64 + (size_t)(t & 1) * 8192;
      const unsigned target = (unsigned)(t + 1);
      unsigned long long w[32];
      bool ok;
      do {
#pragma unroll
        for (int k = 0; k < 32; ++k)
          w[k] = __hip_atomic_load(&src[tid + k * 256], __ATOMIC_RELAXED, __HIP_MEMORY_SCOPE_AGENT);
        ok = true;
#pragma unroll
        for (int k = 0; k < 32; ++k) ok &= ((unsigned)w[k] == target);
      } while (!ok);
      // Word f = tid + k*256 -> batch row b = k, col pair = tid (2-way banks, free).
#pragma unroll
      for (int k = 0; k < 32; ++k)
        *reinterpret_cast<unsigned*>(&h_lds[k][tid * 2]) = (unsigned)(w[k] >> 32);
    }
    __syncthreads();

    // gates(preact) = h @ w_hh^T for this wave's 16 gate-cols.
    floatx4 acc0 = (floatx4)0.f, acc1 = (floatx4)0.f;
#pragma unroll
    for (int q = 0; q < 16; ++q) {
      ushortx8 a0 = *reinterpret_cast<const ushortx8*>(&h_lds[l15][q * 32 + lq * 8]);
      ushortx8 a1 = *reinterpret_cast<const ushortx8*>(&h_lds[16 + l15][q * 32 + lq * 8]);
      acc0 = mfma_bf16(a0, wfrag[q], acc0);
      acc1 = mfma_bf16(a1, wfrag[q], acc1);
    }
#pragma unroll
    for (int r = 0; r < 4; ++r) {
      gate_lds[wave][lq * 4 + r][l15] = acc0[r];
      gate_lds[wave][16 + lq * 4 + r][l15] = acc1[r];
    }
    __syncthreads();

    // Combine: i,f,g,o -> c,h for (b_, col0) and (b_, col0+1); publish tagged h_{t+1}.
    {
      const unsigned short* gx = gx_lds[t & 1];
      float i0 = sigmoidf_(gate_lds[0][b_][j0] + bf2f(gx[(0 * 32 + b_) * 16 + j0]));
      float f0 = sigmoidf_(gate_lds[1][b_][j0] + bf2f(gx[(1 * 32 + b_) * 16 + j0]));
      float g0 = tanhf_(gate_lds[2][b_][j0] + bf2f(gx[(2 * 32 + b_) * 16 + j0]));
      float o0 = sigmoidf_(gate_lds[3][b_][j0] + bf2f(gx[(3 * 32 + b_) * 16 + j0]));
      c_0 = f0 * c_0 + i0 * g0;
      float ha = o0 * tanhf_(c_0);

      float i1 = sigmoidf_(gate_lds[0][b_][j0 + 1] + bf2f(gx[(0 * 32 + b_) * 16 + j0 + 1]));
      float f1 = sigmoidf_(gate_lds[1][b_][j0 + 1] + bf2f(gx[(1 * 32 + b_) * 16 + j0 + 1]));
      float g1 = tanhf_(gate_lds[2][b_][j0 + 1] + bf2f(gx[(2 * 32 + b_) * 16 + j0 + 1]));
      float o1 = sigmoidf_(gate_lds[3][b_][j0 + 1] + bf2f(gx[(3 * 32 + b_) * 16 + j0 + 1]));
      c_1 = f1 * c_1 + i1 * g1;
      float hb = o1 * tanhf_(c_1);

      unsigned data = (unsigned)f2bf(ha) | ((unsigned)f2bf(hb) << 16);
      unsigned long long w = ((unsigned long long)data << 32) | (unsigned long long)(t + 2);
      unsigned long long* hdst = gbuf64 + (size_t)((t + 1) & 1) * 8192;
      __hip_atomic_store(&hdst[b_ * 256 + (col0 >> 1)], w, __ATOMIC_RELAXED, __HIP_MEMORY_SCOPE_AGENT);
      if (t == 511) {
        out[(size_t)b_ * 1024 + col0] = fmaxf(ha, 0.f);
        out[(size_t)b_ * 1024 + col0 + 1] = fmaxf(hb, 0.f);
      }
    }
    // No drain, no flag, no trailing barrier: the tag IS the readiness signal.
  }

  // Tell the burners we're done.
  if (wg == 0 && tid == 0)
    __hip_atomic_store(&flags[0], DONE_MAGIC, __ATOMIC_RELAXED, __HIP_MEMORY_SCOPE_AGENT);
}

// ---------------------------------------------------------------------------
extern "C" void kernel_launch(void* const* d_in, const int* in_sizes, int n_in,
                              void* d_out, int out_size, void* d_ws, size_t ws_size,
                              hipStream_t stream) {
  const float* x      = (const float*)d_in[0];
  const float* h0     = (const float*)d_in[1];
  const float* c0     = (const float*)d_in[2];
  const float* w_ih_f = (const float*)d_in[3];
  const float* w_hh_f = (const float*)d_in[4];
  const float* b_ih_f = (const float*)d_in[5];
  const float* b_hh_f = (const float*)d_in[6];
  const float* w_ih_b = (const float*)d_in[7];
  const float* w_hh_b = (const float*)d_in[8];
  const float* b_ih_b = (const float*)d_in[9];
  const float* b_hh_b = (const float*)d_in[10];
  float* out = (float*)d_out;

  char* ws = (char*)d_ws;
  unsigned short* gxbuf      = (unsigned short*)(ws);                          // 64 MB
  unsigned short* wihbf      = (unsigned short*)(ws + (size_t)67108864);       // 3 MB
  unsigned long long* gbuf64 = (unsigned long long*)(ws + (size_t)67108864 + 3145728);  // 128 KB (2 slots x 8192 u64)
  unsigned* flags            = (unsigned*)(ws + (size_t)67108864 + 3145728 + 131072);   // done word
  float* sink                = (float*)(ws + (size_t)67108864 + 3145728 + 131072 + 1024);  // burner sink

  hipMemsetAsync(flags, 0, 256, stream);
  hipLaunchKernelGGL(cvt_w_kernel, dim3(1536), dim3(256), 0, stream, w_ih_f, wihbf, 1572864);
  hipLaunchKernelGGL(gx_kernel, dim3(8, 512), dim3(256), 0, stream, x, wihbf, b_ih_f, b_hh_f, gxbuf);
  hipLaunchKernelGGL(bwd_kernel, dim3(32), dim3(256), 0, stream, x, h0, c0,
                     w_ih_b, w_hh_b, b_ih_b, b_hh_b, out);
  hipLaunchKernelGGL(lstm_fwd_kernel, dim3(GRID_TOTAL), dim3(256), 0, stream,
                     w_hh_f, gxbuf, h0, c0, gbuf64, flags, sink, out);
}

// Round 5
// 1884.113 us; speedup vs baseline: 1.9185x; 1.0457x over previous
//
#include <hip/hip_runtime.h>

// ---------------------------------------------------------------------------
// Bidirectional LSTM, B=32, T=512, I=768, H=512. Output = relu([h_f(T-1), h_b_first]) [32,1024] fp32.
//   K0 cvt_w:    w_ih_f fp32 -> bf16 (ws)
//   K1 gx:       gx[t][wg][gate][b][j] = x[b,t,:]@w_ih_f^T + b_ih_f + b_hh_f   (bf16, 64 MB ws)
//   K2 bwd:      single LSTM cell on x[:,T-1,:] with (h0[1],c0[1]) -> out[:,512:1024]
//   K3 fwd:      persistent 32 worker WGs + 224 burner WGs, 512 steps.
//
// Round-5 change (single variable): workers are the blocks with blockIdx%8==0
// (wg = blockIdx/8). Under the SPX round-robin blockIdx->XCD mapping this puts
// all 32 workers on ONE XCD (one per CU), so the tagged-mailbox h exchange
// stays inside a single L2 (store ~100cyc + poll-hit ~200cyc) instead of
// paying cross-XCD invalidate/propagation latency (~3.3us/step observed).
// Evidence for L2-served mailbox: round-4 FETCH_SIZE 166MB << 1.07GB minimum
// if polls went to the coherence point. Burners land on the other 7 XCDs and
// keep clocks boosted. If blockIdx%8 is NOT the XCD mapping, workers spread
// exactly as round 4 -> no regression (perf-only heuristic).
// ---------------------------------------------------------------------------

typedef __attribute__((ext_vector_type(4))) float         floatx4;
typedef __attribute__((ext_vector_type(4))) unsigned int  uintx4;
typedef __attribute__((ext_vector_type(8))) unsigned short ushortx8;
typedef __attribute__((ext_vector_type(4))) unsigned short ushortx4;
typedef __attribute__((ext_vector_type(8))) __bf16        bf16x8;

#define NBLK 32        // worker workgroups
#define GRID_TOTAL 256 // workers + burners
#define DONE_MAGIC 0xDEADBEEFu

__device__ __forceinline__ unsigned short f2bf(float f) {
  unsigned u = __builtin_bit_cast(unsigned, f);
  return (unsigned short)((u + 0x7fffu + ((u >> 16) & 1u)) >> 16);  // RNE
}
__device__ __forceinline__ float bf2f(unsigned short h) {
  unsigned u = ((unsigned)h) << 16;
  return __builtin_bit_cast(float, u);
}
__device__ __forceinline__ floatx4 mfma_bf16(ushortx8 a, ushortx8 b, floatx4 c) {
  return __builtin_amdgcn_mfma_f32_16x16x32_bf16(
      __builtin_bit_cast(bf16x8, a), __builtin_bit_cast(bf16x8, b), c, 0, 0, 0);
}
__device__ __forceinline__ float sigmoidf_(float x) { return 1.f / (1.f + __expf(-x)); }
__device__ __forceinline__ float tanhf_(float x) {
  float ax = fabsf(x);
  float e = __expf(-2.f * ax);
  float r = (1.f - e) / (1.f + e);
  return x < 0.f ? -r : r;
}

// --------------------------- K0: weight convert ----------------------------
__global__ void cvt_w_kernel(const float* __restrict__ src, unsigned short* __restrict__ dst, int n) {
  int i = (blockIdx.x * 256 + threadIdx.x) * 4;
  if (i < n) {
    floatx4 v = *reinterpret_cast<const floatx4*>(src + i);
    ushortx4 o;
    o[0] = f2bf(v[0]); o[1] = f2bf(v[1]); o[2] = f2bf(v[2]); o[3] = f2bf(v[3]);
    *reinterpret_cast<ushortx4*>(dst + i) = o;
  }
}

// --------------------------- K1: gx precompute -----------------------------
// grid (8, 512): blockIdx.y = t, blockIdx.x = nb (4 wg-slices each).
// gxbuf layout: [t][wg][gate][b][j] bf16, block (t,wg) = 2048 elements (4 KB).
__global__ __launch_bounds__(256) void gx_kernel(
    const float* __restrict__ x, const unsigned short* __restrict__ w_bf,
    const float* __restrict__ b_ih, const float* __restrict__ b_hh,
    unsigned short* __restrict__ gxbuf) {
  const int t = blockIdx.y;
  const int nb = blockIdx.x;
  const int tid = threadIdx.x;
  const int wave = tid >> 6;       // gate 0..3
  const int lane = tid & 63;
  const int l15 = lane & 15;
  const int lq = lane >> 4;

  __shared__ __align__(16) unsigned short x_lds[32][776];  // 768 + pad 8

  {
    const int row = tid >> 3, c8 = tid & 7;
    const floatx4* src = reinterpret_cast<const floatx4*>(x + ((size_t)row * 512 + t) * 768);
#pragma unroll
    for (int m = 0; m < 24; ++m) {
      int col4 = c8 + m * 8;
      floatx4 v = src[col4];
      ushortx4 o;
      o[0] = f2bf(v[0]); o[1] = f2bf(v[1]); o[2] = f2bf(v[2]); o[3] = f2bf(v[3]);
      *reinterpret_cast<ushortx4*>(&x_lds[row][col4 * 4]) = o;
    }
  }
  __syncthreads();

  const int wgs = nb * 4;
  const ushortx8* brow[4];
#pragma unroll
  for (int nt = 0; nt < 4; ++nt) {
    int n = wave * 512 + (wgs + nt) * 16 + l15;
    brow[nt] = reinterpret_cast<const ushortx8*>(w_bf + (size_t)n * 768);
  }

  floatx4 acc[4][2];
#pragma unroll
  for (int nt = 0; nt < 4; ++nt) { acc[nt][0] = (floatx4)0.f; acc[nt][1] = (floatx4)0.f; }

  for (int q = 0; q < 24; ++q) {
    ushortx8 a0 = *reinterpret_cast<const ushortx8*>(&x_lds[l15][q * 32 + lq * 8]);
    ushortx8 a1 = *reinterpret_cast<const ushortx8*>(&x_lds[16 + l15][q * 32 + lq * 8]);
#pragma unroll
    for (int nt = 0; nt < 4; ++nt) {
      ushortx8 bf = brow[nt][q * 4 + lq];
      acc[nt][0] = mfma_bf16(a0, bf, acc[nt][0]);
      acc[nt][1] = mfma_bf16(a1, bf, acc[nt][1]);
    }
  }

#pragma unroll
  for (int nt = 0; nt < 4; ++nt) {
    int wg = wgs + nt;
    int N = wave * 512 + wg * 16 + l15;
    float bias = b_ih[N] + b_hh[N];
    unsigned short* dst = gxbuf + ((size_t)(t * 32 + wg)) * 2048 + wave * 512 + l15;
#pragma unroll
    for (int m = 0; m < 2; ++m)
#pragma unroll
      for (int r = 0; r < 4; ++r) {
        int b = m * 16 + lq * 4 + r;
        dst[b * 16] = f2bf(acc[nt][m][r] + bias);
      }
  }
}

// --------------------------- K2: backward single step ----------------------
__global__ __launch_bounds__(256) void bwd_kernel(
    const float* __restrict__ x, const float* __restrict__ h0, const float* __restrict__ c0,
    const float* __restrict__ w_ih_b, const float* __restrict__ w_hh_b,
    const float* __restrict__ b_ih_b, const float* __restrict__ b_hh_b,
    float* __restrict__ out) {
  const int wg = blockIdx.x;
  const int tid = threadIdx.x;
  const int wave = tid >> 6;
  const int lane = tid & 63;
  const int l15 = lane & 15;
  const int lq = lane >> 4;

  __shared__ __align__(16) unsigned short cat_lds[32][1288];  // [b][x(768) | h0(512)] + pad 8
  __shared__ __align__(16) float gate_lds[4][32][16];

  {
    const int row = tid >> 3, o8 = tid & 7;
    const floatx4* xs = reinterpret_cast<const floatx4*>(x + ((size_t)row * 512 + 511) * 768);
#pragma unroll
    for (int m = 0; m < 24; ++m) {
      int col4 = o8 + m * 8;
      floatx4 v = xs[col4];
      ushortx4 o;
      o[0] = f2bf(v[0]); o[1] = f2bf(v[1]); o[2] = f2bf(v[2]); o[3] = f2bf(v[3]);
      *reinterpret_cast<ushortx4*>(&cat_lds[row][col4 * 4]) = o;
    }
    const floatx4* hs = reinterpret_cast<const floatx4*>(h0 + (size_t)(32 + row) * 512);
#pragma unroll
    for (int m = 0; m < 16; ++m) {
      int col4 = o8 + m * 8;
      floatx4 v = hs[col4];
      ushortx4 o;
      o[0] = f2bf(v[0]); o[1] = f2bf(v[1]); o[2] = f2bf(v[2]); o[3] = f2bf(v[3]);
      *reinterpret_cast<ushortx4*>(&cat_lds[row][768 + col4 * 4]) = o;
    }
  }
  __syncthreads();

  const int n = wave * 512 + wg * 16 + l15;
  floatx4 acc0 = (floatx4)0.f, acc1 = (floatx4)0.f;
  for (int q = 0; q < 40; ++q) {
    int k0 = q * 32;
    const float* wsrc = (k0 < 768) ? (w_ih_b + (size_t)n * 768 + k0 + lq * 8)
                                   : (w_hh_b + (size_t)n * 512 + (k0 - 768) + lq * 8);
    ushortx8 bf;
#pragma unroll
    for (int j = 0; j < 8; ++j) bf[j] = f2bf(wsrc[j]);
    ushortx8 a0 = *reinterpret_cast<const ushortx8*>(&cat_lds[l15][k0 + lq * 8]);
    ushortx8 a1 = *reinterpret_cast<const ushortx8*>(&cat_lds[16 + l15][k0 + lq * 8]);
    acc0 = mfma_bf16(a0, bf, acc0);
    acc1 = mfma_bf16(a1, bf, acc1);
  }
#pragma unroll
  for (int r = 0; r < 4; ++r) {
    gate_lds[wave][lq * 4 + r][l15] = acc0[r];
    gate_lds[wave][16 + lq * 4 + r][l15] = acc1[r];
  }
  __syncthreads();

  {
    const int jj = tid & 15;
    const int b0 = tid >> 4;
    const int col = wg * 16 + jj;
    float bi[4];
#pragma unroll
    for (int g = 0; g < 4; ++g) bi[g] = b_ih_b[g * 512 + col] + b_hh_b[g * 512 + col];
#pragma unroll
    for (int half = 0; half < 2; ++half) {
      int b = b0 + half * 16;
      float gi = sigmoidf_(gate_lds[0][b][jj] + bi[0]);
      float gf = sigmoidf_(gate_lds[1][b][jj] + bi[1]);
      float gg = tanhf_(gate_lds[2][b][jj] + bi[2]);
      float go = sigmoidf_(gate_lds[3][b][jj] + bi[3]);
      float c = gf * c0[(size_t)(32 + b) * 512 + col] + gi * gg;
      float h = go * tanhf_(c);
      out[(size_t)b * 1024 + 512 + col] = fmaxf(h, 0.f);
    }
  }
}

// --------------------------- K3: persistent forward ------------------------
// Workers: blocks with blockIdx%8==0 (wg = blockIdx/8) -> one XCD under SPX
// round-robin. WG wg owns hidden cols [wg*16, wg*16+16), 512 steps.
// h exchange: gbuf64[slot][b*256 + col/2] = {bf16x2 data (hi32) | tag (lo32)},
// tag = t+1 for h_t in slot t&1. Atomic u64 store/load, relaxed, agent scope.
// Burners (blockIdx%8!=0): dependent-FMA spin until flags[0]==DONE_MAGIC.
__global__ __launch_bounds__(256, 1) void lstm_fwd_kernel(
    const float* __restrict__ w_hh, const unsigned short* __restrict__ gxbuf,
    const float* __restrict__ h0, const float* __restrict__ c0,
    unsigned long long* gbuf64, unsigned* flags, float* sink,
    float* __restrict__ out) {
  const int tid = threadIdx.x;

  if ((blockIdx.x & 7) != 0) {
    // ---- burner: keep the engine clock boosted until the workers finish ----
    __shared__ unsigned sdone;
    float a0 = 1.0f + 1e-7f * (float)(tid + 1);
    float a1 = 1.0f - 1e-7f * (float)(tid + 2);
    float a2 = 1.0f + 2e-7f * (float)(tid + 3);
    float a3 = 1.0f - 2e-7f * (float)(tid + 4);
    const float m0 = 0.99999994f;
    unsigned d;
    do {
#pragma unroll 8
      for (int i = 0; i < 2048; ++i) {
        a0 = fmaf(a0, m0, 1e-7f);
        a1 = fmaf(a1, m0, -1e-7f);
        a2 = fmaf(a2, m0, 2e-7f);
        a3 = fmaf(a3, m0, -2e-7f);
      }
      if (tid == 0)
        sdone = __hip_atomic_load(&flags[0], __ATOMIC_RELAXED, __HIP_MEMORY_SCOPE_AGENT);
      __syncthreads();
      d = sdone;
      __syncthreads();
    } while (d != DONE_MAGIC);
    if (a0 + a1 + a2 + a3 == 3.14159f) sink[blockIdx.x] = a0;  // keep the math alive
    return;
  }

  // ------------------------------- worker -----------------------------------
  const int wg = blockIdx.x >> 3;  // 0..31, all on one XCD if %8 mapping holds
  const int wave = tid >> 6;  // gate 0..3
  const int lane = tid & 63;
  const int l15 = lane & 15;
  const int lq = lane >> 4;

  __shared__ __align__(16) unsigned short h_lds[32][520];    // [b][k], pad 8 -> 2-way banks (free)
  __shared__ __align__(16) float gate_lds[4][32][16];
  __shared__ __align__(16) unsigned short gx_lds[2][2048];   // double-buffered [gate][b][j]

  // One-time: w_hh B-fragments resident in VGPRs (16 k-steps x 8 bf16).
  ushortx8 wfrag[16];
  {
    const int n = wave * 512 + wg * 16 + l15;
    const float* wrow = w_hh + (size_t)n * 512 + lq * 8;
#pragma unroll
    for (int q = 0; q < 16; ++q) {
      ushortx8 f;
#pragma unroll
      for (int j = 0; j < 8; ++j) f[j] = f2bf(wrow[q * 32 + j]);
      wfrag[q] = f;
    }
  }

  // Per-thread cell state: 1 batch row, 2 adjacent cols (one tagged u64 publish).
  const int b_ = tid >> 3;           // 0..31
  const int j0 = (tid & 7) * 2;      // 0,2,..,14
  const int col0 = wg * 16 + j0;
  float c_0 = c0[(size_t)b_ * 512 + col0];
  float c_1 = c0[(size_t)b_ * 512 + col0 + 1];

  // Publish h0 into slot 0 with tag 1. Fire-and-forget.
  {
    unsigned data = (unsigned)f2bf(h0[(size_t)b_ * 512 + col0]) |
                    ((unsigned)f2bf(h0[(size_t)b_ * 512 + col0 + 1]) << 16);
    unsigned long long w = ((unsigned long long)data << 32) | 1ull;
    __hip_atomic_store(&gbuf64[b_ * 256 + (col0 >> 1)], w, __ATOMIC_RELAXED, __HIP_MEMORY_SCOPE_AGENT);
  }

  const uintx4* gxp = reinterpret_cast<const uintx4*>(gxbuf);
  uintx4 gxreg = gxp[(size_t)(0 * 32 + wg) * 256 + tid];  // prefetch t=0

#pragma unroll 1
  for (int t = 0; t < 512; ++t) {
    // gx[t] regs -> LDS (buffer t&1); prefetch gx[t+1].
    *reinterpret_cast<uintx4*>(&gx_lds[t & 1][tid * 8]) = gxreg;
    if (t + 1 < 512) gxreg = gxp[(size_t)((t + 1) * 32 + wg) * 256 + tid];

    // Poll-read h_t: 32 tagged u64 words per thread from slot t&1.
    {
      unsigned long long* src = gbuf64 + (size_t)(t & 1) * 8192;
      const unsigned target = (unsigned)(t + 1);
      unsigned long long w[32];
      bool ok;
      do {
#pragma unroll
        for (int k = 0; k < 32; ++k)
          w[k] = __hip_atomic_load(&src[tid + k * 256], __ATOMIC_RELAXED, __HIP_MEMORY_SCOPE_AGENT);
        ok = true;
#pragma unroll
        for (int k = 0; k < 32; ++k) ok &= ((unsigned)w[k] == target);
      } while (!ok);
      // Word f = tid + k*256 -> batch row b = k, col pair = tid (2-way banks, free).
#pragma unroll
      for (int k = 0; k < 32; ++k)
        *reinterpret_cast<unsigned*>(&h_lds[k][tid * 2]) = (unsigned)(w[k] >> 32);
    }
    __syncthreads();

    // gates(preact) = h @ w_hh^T for this wave's 16 gate-cols.
    floatx4 acc0 = (floatx4)0.f, acc1 = (floatx4)0.f;
#pragma unroll
    for (int q = 0; q < 16; ++q) {
      ushortx8 a0 = *reinterpret_cast<const ushortx8*>(&h_lds[l15][q * 32 + lq * 8]);
      ushortx8 a1 = *reinterpret_cast<const ushortx8*>(&h_lds[16 + l15][q * 32 + lq * 8]);
      acc0 = mfma_bf16(a0, wfrag[q], acc0);
      acc1 = mfma_bf16(a1, wfrag[q], acc1);
    }
#pragma unroll
    for (int r = 0; r < 4; ++r) {
      gate_lds[wave][lq * 4 + r][l15] = acc0[r];
      gate_lds[wave][16 + lq * 4 + r][l15] = acc1[r];
    }
    __syncthreads();

    // Combine: i,f,g,o -> c,h for (b_, col0) and (b_, col0+1); publish tagged h_{t+1}.
    {
      const unsigned short* gx = gx_lds[t & 1];
      float i0 = sigmoidf_(gate_lds[0][b_][j0] + bf2f(gx[(0 * 32 + b_) * 16 + j0]));
      float f0 = sigmoidf_(gate_lds[1][b_][j0] + bf2f(gx[(1 * 32 + b_) * 16 + j0]));
      float g0 = tanhf_(gate_lds[2][b_][j0] + bf2f(gx[(2 * 32 + b_) * 16 + j0]));
      float o0 = sigmoidf_(gate_lds[3][b_][j0] + bf2f(gx[(3 * 32 + b_) * 16 + j0]));
      c_0 = f0 * c_0 + i0 * g0;
      float ha = o0 * tanhf_(c_0);

      float i1 = sigmoidf_(gate_lds[0][b_][j0 + 1] + bf2f(gx[(0 * 32 + b_) * 16 + j0 + 1]));
      float f1 = sigmoidf_(gate_lds[1][b_][j0 + 1] + bf2f(gx[(1 * 32 + b_) * 16 + j0 + 1]));
      float g1 = tanhf_(gate_lds[2][b_][j0 + 1] + bf2f(gx[(2 * 32 + b_) * 16 + j0 + 1]));
      float o1 = sigmoidf_(gate_lds[3][b_][j0 + 1] + bf2f(gx[(3 * 32 + b_) * 16 + j0 + 1]));
      c_1 = f1 * c_1 + i1 * g1;
      float hb = o1 * tanhf_(c_1);

      unsigned data = (unsigned)f2bf(ha) | ((unsigned)f2bf(hb) << 16);
      unsigned long long w = ((unsigned long long)data << 32) | (unsigned long long)(t + 2);
      unsigned long long* hdst = gbuf64 + (size_t)((t + 1) & 1) * 8192;
      __hip_atomic_store(&hdst[b_ * 256 + (col0 >> 1)], w, __ATOMIC_RELAXED, __HIP_MEMORY_SCOPE_AGENT);
      if (t == 511) {
        out[(size_t)b_ * 1024 + col0] = fmaxf(ha, 0.f);
        out[(size_t)b_ * 1024 + col0 + 1] = fmaxf(hb, 0.f);
      }
    }
    // No drain, no flag, no trailing barrier: the tag IS the readiness signal.
  }

  // Tell the burners we're done.
  if (wg == 0 && tid == 0)
    __hip_atomic_store(&flags[0], DONE_MAGIC, __ATOMIC_RELAXED, __HIP_MEMORY_SCOPE_AGENT);
}

// ---------------------------------------------------------------------------
extern "C" void kernel_launch(void* const* d_in, const int* in_sizes, int n_in,
                              void* d_out, int out_size, void* d_ws, size_t ws_size,
                              hipStream_t stream) {
  const float* x      = (const float*)d_in[0];
  const float* h0     = (const float*)d_in[1];
  const float* c0     = (const float*)d_in[2];
  const float* w_ih_f = (const float*)d_in[3];
  const float* w_hh_f = (const float*)d_in[4];
  const float* b_ih_f = (const float*)d_in[5];
  const float* b_hh_f = (const float*)d_in[6];
  const float* w_ih_b = (const float*)d_in[7];
  const float* w_hh_b = (const float*)d_in[8];
  const float* b_ih_b = (const float*)d_in[9];
  const float* b_hh_b = (const float*)d_in[10];
  float* out = (float*)d_out;

  char* ws = (char*)d_ws;
  unsigned short* gxbuf      = (unsigned short*)(ws);                          // 64 MB
  unsigned short* wihbf      = (unsigned short*)(ws + (size_t)67108864);       // 3 MB
  unsigned long long* gbuf64 = (unsigned long long*)(ws + (size_t)67108864 + 3145728);  // 128 KB (2 slots x 8192 u64)
  unsigned* flags            = (unsigned*)(ws + (size_t)67108864 + 3145728 + 131072);   // done word
  float* sink                = (float*)(ws + (size_t)67108864 + 3145728 + 131072 + 1024);  // burner sink

  hipMemsetAsync(flags, 0, 256, stream);
  hipLaunchKernelGGL(cvt_w_kernel, dim3(1536), dim3(256), 0, stream, w_ih_f, wihbf, 1572864);
  hipLaunchKernelGGL(gx_kernel, dim3(8, 512), dim3(256), 0, stream, x, wihbf, b_ih_f, b_hh_f, gxbuf);
  hipLaunchKernelGGL(bwd_kernel, dim3(32), dim3(256), 0, stream, x, h0, c0,
                     w_ih_b, w_hh_b, b_ih_b, b_hh_b, out);
  hipLaunchKernelGGL(lstm_fwd_kernel, dim3(GRID_TOTAL), dim3(256), 0, stream,
                     w_hh_f, gxbuf, h0, c0, gbuf64, flags, sink, out);
}